// Round 6
// baseline (598.463 us; speedup 1.0000x reference)
//
#include <hip/hip_runtime.h>
#include <hip/hip_bf16.h>
#include <cstdint>
#include <cstddef>

typedef __attribute__((ext_vector_type(8))) short short8;
typedef __attribute__((ext_vector_type(4))) float f32x4;

// ---- bf16 split helpers (pure bit ops, RN) ----
__device__ __forceinline__ unsigned short f32_to_bf16_rn(float f) {
  unsigned int u = __float_as_uint(f);
  u += 0x7FFFu + ((u >> 16) & 1u);
  return (unsigned short)(u >> 16);
}
__device__ __forceinline__ float bf16_to_f32(unsigned short b) {
  return __uint_as_float(((unsigned int)b) << 16);
}
__device__ __forceinline__ void split_bf(float f, unsigned short& hi, unsigned short& lo) {
  hi = f32_to_bf16_rn(f);
  lo = f32_to_bf16_rn(f - bf16_to_f32(hi));
}
__device__ __forceinline__ float4 bf4_to_f4(ushort4 v) {
  float4 r;
  r.x = bf16_to_f32(v.x); r.y = bf16_to_f32(v.y);
  r.z = bf16_to_f32(v.z); r.w = bf16_to_f32(v.w);
  return r;
}

// direct global->LDS 16B async copy; LDS dest = wave-uniform base + lane*16
__device__ __forceinline__ void gload16(const void* g, const void* l) {
  __builtin_amdgcn_global_load_lds(
      (const __attribute__((address_space(1))) unsigned int*)g,
      (__attribute__((address_space(3))) unsigned int*)l, 16, 0, 0);
}

// ---------------- init: zero cnt, cursor, g ----------------
__global__ void k_init(int* cnt, int* cursor, float* g, int M, int GH) {
  int i = blockIdx.x * blockDim.x + threadIdx.x;
  int stride = gridDim.x * blockDim.x;
  for (int x = i; x < M; x += stride) { cnt[x] = 0; cursor[x] = 0; }
  for (int x = i; x < GH; x += stride) g[x] = 0.f;
}

// ---------------- degree histogram (incoming edges) ----------------
__global__ void k_count(const int* __restrict__ dst, int* __restrict__ cnt, int E) {
  int i = blockIdx.x * blockDim.x + threadIdx.x;
  for (int e = i; e < E; e += gridDim.x * blockDim.x)
    atomicAdd(&cnt[dst[e]], 1);
}

__global__ void k_dinv(const int* __restrict__ cnt, float* __restrict__ dinv, int M) {
  int i = blockIdx.x * blockDim.x + threadIdx.x;
  if (i < M) dinv[i] = rsqrtf((float)(cnt[i] + 1));  // +1 self loop
}

// ---------------- 2-level exclusive scan over cnt -> row_ptr ----------------
__global__ void k_scan1(const int* __restrict__ cnt, int* __restrict__ excl,
                        int* __restrict__ bsum, int M) {
  __shared__ int s[256];
  int gid = blockIdx.x * 256 + threadIdx.x;
  int v = (gid < M) ? cnt[gid] : 0;
  s[threadIdx.x] = v;
  __syncthreads();
  for (int off = 1; off < 256; off <<= 1) {
    int t = (threadIdx.x >= off) ? s[threadIdx.x - off] : 0;
    __syncthreads();
    s[threadIdx.x] += t;
    __syncthreads();
  }
  if (gid < M) excl[gid] = s[threadIdx.x] - v;
  if (threadIdx.x == 255) bsum[blockIdx.x] = s[255];
}

__global__ void k_scan2(int* bsum, int nb) {
  __shared__ int s[256];
  int v = (threadIdx.x < nb) ? bsum[threadIdx.x] : 0;
  s[threadIdx.x] = v;
  __syncthreads();
  for (int off = 1; off < 256; off <<= 1) {
    int t = (threadIdx.x >= off) ? s[threadIdx.x - off] : 0;
    __syncthreads();
    s[threadIdx.x] += t;
    __syncthreads();
  }
  if (threadIdx.x < nb) bsum[threadIdx.x] = s[threadIdx.x] - v;  // exclusive
}

__global__ void k_scan3(int* row_ptr, const int* __restrict__ bsum, int M, int E) {
  int gid = blockIdx.x * 256 + threadIdx.x;
  if (gid < M) row_ptr[gid] += bsum[blockIdx.x];
  if (gid == 0) row_ptr[M] = E;
}

// ---------------- CSR scatter (by dst) ----------------
__global__ void k_scatter(const int* __restrict__ src, const int* __restrict__ dst,
                          const int* __restrict__ row_ptr, int* __restrict__ cursor,
                          int* __restrict__ eidx, int E) {
  int i = blockIdx.x * blockDim.x + threadIdx.x;
  for (int e = i; e < E; e += gridDim.x * blockDim.x) {
    int d = dst[e];
    int pos = atomicAdd(&cursor[d], 1);
    eidx[row_ptr[d] + pos] = src[e];
  }
}

// ---------------- W transpose + split: W[K][256] f32 -> WT_hi/lo[256][K] bf16 ----------------
__global__ void k_wtrans(const float* __restrict__ W, unsigned short* __restrict__ WTh,
                         unsigned short* __restrict__ WTl, int K) {
  int idx = blockIdx.x * 256 + threadIdx.x;
  if (idx >= K * 256) return;
  int n = idx / K, k = idx % K;  // writes coalesced in k
  float v = W[(size_t)k * 256 + n];
  unsigned short h, l;
  split_bf(v, h, l);
  WTh[(size_t)n * K + k] = h;
  WTl[(size_t)n * K + k] = l;
}

// ---------------- split-bf16 MFMA GEMM (global_load_lds staging) ----------------
// outbf[r, 0:256] = bf16( (A[r,0:K] @ W[0:K,0:256]) * dinv[r] )
#define BM 64
#define BN 256
#define BK 32

template <bool AF32>
__global__ __launch_bounds__(256) void k_gemm(
    const float* __restrict__ Af,
    const unsigned short* __restrict__ Ahg, const unsigned short* __restrict__ Alg,
    const unsigned short* __restrict__ WTh, const unsigned short* __restrict__ WTl,
    const float* __restrict__ dinv, unsigned short* __restrict__ out, int M, int K) {
  // LDS map (bytes):
  //  AF32:  Af32[0,8K) | Ah[8K,12K) | Al[12K,16K) | Bh[16K,32K) | Bl[32K,48K)
  //  bf16:  Ah[0,4K)   | Al[4K,8K)  | Bh[8K,24K)  | Bl[24K,40K)
  constexpr int AHB = AF32 ? 8192 : 0;
  constexpr int ALB = AHB + 4096;
  constexpr int BHB = AF32 ? 16384 : 8192;
  constexpr int BLB = BHB + 16384;
  constexpr int LDSZ = BLB + 16384;
  __shared__ __align__(16) char lds[LDSZ];

  const int tid = threadIdx.x;
  const int lane = tid & 63;
  const int wv = tid >> 6;  // wave -> col block wv*64
  const int row0 = blockIdx.x * BM;
  const int ASTEP = AF32 ? BK * 4 : BK * 2;  // source bytes per K-step

  // 40 chunks of 1KB per K-step: 0..7 = A region, 8..39 = B region.
  // Wave w owns chunks {w+4i}. Source chunk index is XOR-preswizzled so that
  // the linear LDS layout + XOR'd ds_read is bank-conflict-free (<=2-way).
  const char* gsrc[10];
  unsigned ldsoff[10];
#pragma unroll
  for (int i = 0; i < 10; ++i) {
    int c = wv + 4 * i;
    if (i < 2) {  // A chunks (c in 0..7)
      ldsoff[i] = (unsigned)(c * 1024);
      if constexpr (AF32) {
        int r = c * 8 + (lane >> 3);             // row 0..63 (128B rows)
        int sslot = (lane & 7) ^ (r & 7);        // 16B chunk preswizzle
        int gr = row0 + r; gr = gr < M ? gr : (M - 1);  // clamp (no HW masking)
        gsrc[i] = (const char*)(Af + (size_t)gr * K + sslot * 4);
      } else {
        int plane = c >> 2;                      // 0=Ah 1=Al
        int r = (c & 3) * 16 + (lane >> 2);      // row 0..63 (64B rows)
        int sslot = (lane & 3) ^ ((r >> 1) & 3);
        int gr = row0 + r; gr = gr < M ? gr : (M - 1);
        const unsigned short* base = plane ? Alg : Ahg;
        gsrc[i] = (const char*)(base + (size_t)gr * K + sslot * 8);
      }
    } else {  // B chunks (cb in 0..31)
      int cb = c - 8;
      ldsoff[i] = (unsigned)(BHB + cb * 1024);
      int plane = cb >> 4;                       // 0=Bh 1=Bl
      int col = (cb & 15) * 16 + (lane >> 2);    // col 0..255
      int sslot = (lane & 3) ^ ((col >> 1) & 3);
      const unsigned short* base = plane ? WTl : WTh;
      gsrc[i] = (const char*)(base + (size_t)col * K + sslot * 8);
    }
  }

  f32x4 acc[4][4] = {};  // [m][n]
  const int fr = lane & 15;
  const int ks = lane >> 4;  // k-slot 0..3 (8 bf16 each)

  for (int k0 = 0; k0 < K; k0 += BK) {
    // ---- issue direct-to-LDS loads (10 per wave) ----
#pragma unroll
    for (int i = 0; i < 10; ++i) {
      gload16(gsrc[i], lds + ldsoff[i]);
      gsrc[i] += (i < 2) ? ASTEP : (BK * 2);
    }
    __syncthreads();  // compiler drains vmcnt before s_barrier -> data ready

    if constexpr (AF32) {
      // convert staged f32 A -> Ah/Al planes (each element converted once)
      int r = tid >> 2, q = tid & 3, rx = r & 7;
      float4 f0 = *(const float4*)&lds[(size_t)r * 128 + (((2 * q) ^ rx) * 16)];
      float4 f1 = *(const float4*)&lds[(size_t)r * 128 + (((2 * q + 1) ^ rx) * 16)];
      float f[8] = {f0.x, f0.y, f0.z, f0.w, f1.x, f1.y, f1.z, f1.w};
      short8 hv, lv;
#pragma unroll
      for (int j = 0; j < 8; ++j) {
        unsigned short h, l;
        split_bf(f[j], h, l);
        hv[j] = (short)h; lv[j] = (short)l;
      }
      int so = (q ^ ((r >> 1) & 3)) * 16;
      *(short8*)&lds[AHB + r * 64 + so] = hv;
      *(short8*)&lds[ALB + r * 64 + so] = lv;
      __syncthreads();
    }

    // ---- fragments + MFMA (3 per pair: hh + hl + lh) ----
    short8 ah[4], al[4];
#pragma unroll
    for (int m = 0; m < 4; ++m) {
      int rr = m * 16 + fr;
      int so = (ks ^ ((rr >> 1) & 3)) * 16;
      ah[m] = *(const short8*)&lds[AHB + rr * 64 + so];
      al[m] = *(const short8*)&lds[ALB + rr * 64 + so];
    }
#pragma unroll
    for (int n = 0; n < 4; ++n) {
      int cc = wv * 64 + n * 16 + fr;
      int so = (ks ^ ((cc >> 1) & 3)) * 16;
      short8 bh = *(const short8*)&lds[BHB + cc * 64 + so];
      short8 bl = *(const short8*)&lds[BLB + cc * 64 + so];
#pragma unroll
      for (int m = 0; m < 4; ++m) {
        acc[m][n] = __builtin_amdgcn_mfma_f32_16x16x32_bf16(ah[m], bh, acc[m][n], 0, 0, 0);
        acc[m][n] = __builtin_amdgcn_mfma_f32_16x16x32_bf16(ah[m], bl, acc[m][n], 0, 0, 0);
        acc[m][n] = __builtin_amdgcn_mfma_f32_16x16x32_bf16(al[m], bh, acc[m][n], 0, 0, 0);
      }
    }
    __syncthreads();  // protect LDS from next-step overwrite
  }

  // ---- epilogue: C/D layout col=lane&15, row=(lane>>4)*4+reg (m89-verified) ----
  const int rq = (lane >> 4) * 4;
#pragma unroll
  for (int m = 0; m < 4; ++m) {
#pragma unroll
    for (int r = 0; r < 4; ++r) {
      int gr = row0 + m * 16 + rq + r;
      if (gr < M) {
        float s = dinv[gr];
#pragma unroll
        for (int n = 0; n < 4; ++n)
          out[(size_t)gr * BN + wv * 64 + n * 16 + fr] = f32_to_bf16_rn(acc[m][n][r] * s);
      }
    }
  }
}

// ---------------- aggregate: h[i] = relu(dinv[i]*(hws[i] + sum_{e:dst=i} hws[src]) + b)
// hws is bf16 [M][256]; writes hi/lo bf16 (GEMM input) OR f32 (pool input) --------
__global__ __launch_bounds__(64) void k_aggregate(
    const unsigned short* __restrict__ hws, const int* __restrict__ eidx,
    const int* __restrict__ row_ptr, const float* __restrict__ dinv,
    const float* __restrict__ bias, unsigned short* __restrict__ out_hi,
    unsigned short* __restrict__ out_lo, float* __restrict__ out_f32, int M) {
  int i = blockIdx.x;
  if (i >= M) return;
  int t = threadIdx.x;  // 64 threads x 4 feats = 256
  float4 acc = bf4_to_f4(*(const ushort4*)(hws + (size_t)i * 256 + t * 4));  // self loop
  int beg = row_ptr[i], end = row_ptr[i + 1];
  int e = beg;
  // unroll x4: 4 row-gathers in flight per wave
  for (; e + 4 <= end; e += 4) {
    int s0 = eidx[e + 0], s1 = eidx[e + 1], s2 = eidx[e + 2], s3 = eidx[e + 3];
    ushort4 v0 = *(const ushort4*)(hws + (size_t)s0 * 256 + t * 4);
    ushort4 v1 = *(const ushort4*)(hws + (size_t)s1 * 256 + t * 4);
    ushort4 v2 = *(const ushort4*)(hws + (size_t)s2 * 256 + t * 4);
    ushort4 v3 = *(const ushort4*)(hws + (size_t)s3 * 256 + t * 4);
    float4 f0 = bf4_to_f4(v0), f1 = bf4_to_f4(v1);
    float4 f2 = bf4_to_f4(v2), f3 = bf4_to_f4(v3);
    acc.x += (f0.x + f1.x) + (f2.x + f3.x);
    acc.y += (f0.y + f1.y) + (f2.y + f3.y);
    acc.z += (f0.z + f1.z) + (f2.z + f3.z);
    acc.w += (f0.w + f1.w) + (f2.w + f3.w);
  }
  for (; e < end; ++e) {
    int s = eidx[e];
    float4 v = bf4_to_f4(*(const ushort4*)(hws + (size_t)s * 256 + t * 4));
    acc.x += v.x; acc.y += v.y; acc.z += v.z; acc.w += v.w;
  }
  float d = dinv[i];
  float4 b = *(const float4*)(bias + t * 4);
  float r[4];
  r[0] = fmaxf(fmaf(acc.x, d, b.x), 0.f);
  r[1] = fmaxf(fmaf(acc.y, d, b.y), 0.f);
  r[2] = fmaxf(fmaf(acc.z, d, b.z), 0.f);
  r[3] = fmaxf(fmaf(acc.w, d, b.w), 0.f);
  if (out_f32) {
    float4 o; o.x = r[0]; o.y = r[1]; o.z = r[2]; o.w = r[3];
    *(float4*)(out_f32 + (size_t)i * 256 + t * 4) = o;
  } else {
    ushort4 hv, lv;
    unsigned short h, l;
    split_bf(r[0], h, l); hv.x = h; lv.x = l;
    split_bf(r[1], h, l); hv.y = h; lv.y = l;
    split_bf(r[2], h, l); hv.z = h; lv.z = l;
    split_bf(r[3], h, l); hv.w = h; lv.w = l;
    *(ushort4*)(out_hi + (size_t)i * 256 + t * 4) = hv;
    *(ushort4*)(out_lo + (size_t)i * 256 + t * 4) = lv;
  }
}

// ---------------- segment max pool (batch sorted) ----------------
__global__ __launch_bounds__(256) void k_pool(const float* __restrict__ h,
                                              const int* __restrict__ batch,
                                              float* __restrict__ g, int M) {
  int node0 = blockIdx.x * 32;
  if (node0 >= M) return;
  int t = threadIdx.x;
  int nEnd = min(node0 + 32, M);
  int cur = batch[node0];
  float acc = 0.f;  // post-relu values >= 0
  for (int n = node0; n < nEnd; ++n) {
    int b = batch[n];
    if (b != cur) {
      atomicMax((int*)&g[(size_t)cur * 256 + t], __float_as_int(acc));
      acc = 0.f; cur = b;
    }
    acc = fmaxf(acc, h[(size_t)n * 256 + t]);
  }
  atomicMax((int*)&g[(size_t)cur * 256 + t], __float_as_int(acc));
}

// ---------------- classifier: log_softmax(g @ Wl + bl) ----------------
__global__ __launch_bounds__(256) void k_classify(const float* __restrict__ g,
                                                  const float* __restrict__ Wl,
                                                  const float* __restrict__ bl,
                                                  float* __restrict__ out) {
  __shared__ float sg[256];
  __shared__ float logits[10];
  int b = blockIdx.x;
  sg[threadIdx.x] = g[(size_t)b * 256 + threadIdx.x];
  __syncthreads();
  if (threadIdx.x < 10) {
    float s = bl[threadIdx.x];
    for (int k = 0; k < 256; ++k) s = fmaf(sg[k], Wl[k * 10 + threadIdx.x], s);
    logits[threadIdx.x] = s;
  }
  __syncthreads();
  if (threadIdx.x == 0) {
    float m = logits[0];
    for (int c = 1; c < 10; c++) m = fmaxf(m, logits[c]);
    float sum = 0.f;
    for (int c = 0; c < 10; c++) sum += expf(logits[c] - m);
    float lse = m + logf(sum);
    for (int c = 0; c < 10; c++) out[b * 10 + c] = logits[c] - lse;
  }
}

static inline size_t align256(size_t x) { return (x + 255) & ~(size_t)255; }

extern "C" void kernel_launch(void* const* d_in, const int* in_sizes, int n_in,
                              void* d_out, int out_size, void* d_ws, size_t ws_size,
                              hipStream_t stream) {
  const float* x   = (const float*)d_in[0];
  const int*   ei  = (const int*)d_in[1];
  const int*   bat = (const int*)d_in[2];
  const float* W1  = (const float*)d_in[3];
  const float* b1  = (const float*)d_in[4];
  const float* W2  = (const float*)d_in[5];
  const float* b2  = (const float*)d_in[6];
  const float* W3  = (const float*)d_in[7];
  const float* b3  = (const float*)d_in[8];
  const float* Wl  = (const float*)d_in[9];
  const float* bl  = (const float*)d_in[10];
  float* out = (float*)d_out;

  const int M = in_sizes[0] / 512;  // 50000
  const int E = in_sizes[1] / 2;    // 800000
  const int G = out_size / 10;      // 64
  const int K1 = 512, H = 256;

  const int* src = ei;
  const int* dst = ei + E;

  char* p = (char*)d_ws;
  size_t off = 0;
  float* p_dinv = (float*)(p + off); off = align256(off + (size_t)M * 4);
  int* cnt      = (int*)(p + off);   off = align256(off + (size_t)M * 4);
  int* cursor   = (int*)(p + off);   off = align256(off + (size_t)M * 4);
  int* row_ptr  = (int*)(p + off);   off = align256(off + ((size_t)M + 1) * 4);
  int* bsum     = (int*)(p + off);   off = align256(off + 256 * 4);
  int* eidx     = (int*)(p + off);   off = align256(off + (size_t)E * 4);
  float* g      = (float*)(p + off); off = align256(off + (size_t)G * H * 4);
  unsigned short* WT1h = (unsigned short*)(p + off); off = align256(off + (size_t)H * K1 * 2);
  unsigned short* WT1l = (unsigned short*)(p + off); off = align256(off + (size_t)H * K1 * 2);
  unsigned short* WT2h = (unsigned short*)(p + off); off = align256(off + (size_t)H * H * 2);
  unsigned short* WT2l = (unsigned short*)(p + off); off = align256(off + (size_t)H * H * 2);
  unsigned short* WT3h = (unsigned short*)(p + off); off = align256(off + (size_t)H * H * 2);
  unsigned short* WT3l = (unsigned short*)(p + off); off = align256(off + (size_t)H * H * 2);
  unsigned short* hws = (unsigned short*)(p + off); off = align256(off + (size_t)M * H * 2);
  unsigned short* h_hi = (unsigned short*)(p + off); off += (size_t)M * H * 2;  // no pad:
  unsigned short* h_lo = (unsigned short*)(p + off); off = align256(off + (size_t)M * H * 2);
  float* bufC = (float*)h_hi;  // layer-3 f32 output aliases h_hi+h_lo (both dead by then)
  (void)ws_size;

  int nb = (M + 255) / 256;

  k_init<<<256, 256, 0, stream>>>(cnt, cursor, g, M, G * H);
  k_count<<<1024, 256, 0, stream>>>(dst, cnt, E);
  k_dinv<<<nb, 256, 0, stream>>>(cnt, p_dinv, M);
  k_scan1<<<nb, 256, 0, stream>>>(cnt, row_ptr, bsum, M);
  k_scan2<<<1, 256, 0, stream>>>(bsum, nb);
  k_scan3<<<nb, 256, 0, stream>>>(row_ptr, bsum, M, E);
  k_scatter<<<1024, 256, 0, stream>>>(src, dst, row_ptr, cursor, eidx, E);

  k_wtrans<<<(H * K1 + 255) / 256, 256, 0, stream>>>(W1, WT1h, WT1l, K1);
  k_wtrans<<<(H * H + 255) / 256, 256, 0, stream>>>(W2, WT2h, WT2l, H);
  k_wtrans<<<(H * H + 255) / 256, 256, 0, stream>>>(W3, WT3h, WT3l, H);

  int gblk = (M + BM - 1) / BM;
  // layer 1 (A = x, f32, K=512)
  k_gemm<true><<<gblk, 256, 0, stream>>>(x, nullptr, nullptr, WT1h, WT1l, p_dinv, hws, M, K1);
  k_aggregate<<<M, 64, 0, stream>>>(hws, eidx, row_ptr, p_dinv, b1, h_hi, h_lo, nullptr, M);
  // layer 2 (A = h hi/lo, K=256)
  k_gemm<false><<<gblk, 256, 0, stream>>>(nullptr, h_hi, h_lo, WT2h, WT2l, p_dinv, hws, M, H);
  k_aggregate<<<M, 64, 0, stream>>>(hws, eidx, row_ptr, p_dinv, b2, h_hi, h_lo, nullptr, M);
  // layer 3 -> f32 for pool
  k_gemm<false><<<gblk, 256, 0, stream>>>(nullptr, h_hi, h_lo, WT3h, WT3l, p_dinv, hws, M, H);
  k_aggregate<<<M, 64, 0, stream>>>(hws, eidx, row_ptr, p_dinv, b3, nullptr, nullptr, bufC, M);

  k_pool<<<(M + 31) / 32, 256, 0, stream>>>(bufC, bat, g, M);
  k_classify<<<G, 256, 0, stream>>>(g, Wl, bl, out);
}